// Round 1
// baseline (3318.800 us; speedup 1.0000x reference)
//
#include <hip/hip_runtime.h>
#include <cstdint>
#include <cstddef>

#define BB 512
#define TT 1024
#define FF 128
#define HH 128
#define AA 16

// One block per batch element, 128 threads (2 waves). Thread tid owns h=tid.
// Per-thread register-resident weights: W1 row (128f), W2 row (128f), W3 16-seg.
// Spikes communicated as FLOATS in LDS -> cur2/out are dense fmaf sums
// (fmaf(0,w,s)==s exactly, fmaf(1,w,s)==s+w exactly => bit-identical to the
// previous sparse-accumulation kernel, same accumulator split and order).
// x rows double-buffered in LDS, prefetched one step ahead (load issued at
// step top, ds_write at step bottom; barriers never drain vmcnt).
__global__ __launch_bounds__(128, 1) void dsqn_fused(
    const float* __restrict__ X,      // (B,T,F)
    const float* __restrict__ hid,    // (B,1,2,H)
    const float* __restrict__ W1,     // (H,F)
    const float* __restrict__ b1,     // (H)
    const float* __restrict__ beta1,  // (H)
    const float* __restrict__ W2,     // (H,H)
    const float* __restrict__ b2,     // (H)
    const float* __restrict__ beta2,  // (H)
    const float* __restrict__ W3,     // (A,H)
    const float* __restrict__ b3,     // (A)
    float* __restrict__ out)          // (B,T,A)
{
    __shared__ __align__(16) float xsh[2][FF];   // double-buffered x row
    __shared__ __align__(16) float spk1f[HH];    // spikes layer 1 as floats
    __shared__ __align__(16) float spk2f[HH];    // spikes layer 2 as floats
    __shared__ __align__(16) float partials[128];
    __shared__ __align__(16) float obuf[8 * AA]; // 8-step output batch

    const int tid = threadIdx.x;
    const int b = blockIdx.x;
    const int g = tid >> 4, a = tid & 15;

    // ---- persistent per-thread weights (VGPRs) ----
    float4 w1q[32], w2q[32], w3s[4];
    {
        const float4* w1p = (const float4*)(W1 + tid * FF);
        const float4* w2p = (const float4*)(W2 + tid * HH);
        #pragma unroll
        for (int q = 0; q < 32; ++q) { w1q[q] = w1p[q]; w2q[q] = w2p[q]; }
        const float4* w3p = (const float4*)(W3 + a * HH + g * 16);
        #pragma unroll
        for (int q = 0; q < 4; ++q) w3s[q] = w3p[q];
    }

    float mem1 = hid[b * 2 * HH + tid];
    float mem2 = hid[b * 2 * HH + HH + tid];
    const float b1h = b1[tid];
    const float b2h = b2[tid];
    const float bt1 = fminf(fmaxf(beta1[tid], 0.f), 1.f);
    const float bt2 = fminf(fmaxf(beta2[tid], 0.f), 1.f);
    const float b3a = (tid < AA) ? b3[tid] : 0.f;

    const float* xrow = X + (size_t)b * TT * FF;
    float* orow = out + (size_t)b * TT * AA;

    // stage x[0]
    xsh[0][tid] = xrow[tid];
    asm volatile("s_waitcnt lgkmcnt(0)\n\ts_barrier" ::: "memory");

    for (int t = 0; t < TT; ++t) {
        const int cur = t & 1;

        // prefetch x[t+1] into a register (consumed by ds_write at step bottom;
        // compiler places the vmcnt wait there -> HBM latency hides under step)
        const float xn = (t + 1 < TT) ? xrow[FF + tid] : 0.f;

        // ---- cur1[h] = x . W1[h,:] + b1[h] (same split/order as before) ----
        const float4* xq = (const float4*)xsh[cur];
        float s0 = 0.f, s1 = 0.f, s2 = 0.f, s3 = 0.f;
        #pragma unroll
        for (int q = 0; q < 32; ++q) {
            float4 xv = xq[q];
            s0 = fmaf(xv.x, w1q[q].x, s0);
            s1 = fmaf(xv.y, w1q[q].y, s1);
            s2 = fmaf(xv.z, w1q[q].z, s2);
            s3 = fmaf(xv.w, w1q[q].w, s3);
        }
        const float cur1 = ((s0 + s1) + (s2 + s3)) + b1h;

        // ---- LIF1: reset uses OLD mem ----
        const float r1 = (mem1 > 1.0f) ? 1.0f : 0.0f;
        mem1 = bt1 * mem1 + cur1 - r1;
        const float sp1 = ((mem1 - 1.0f) > 0.0f) ? 1.0f : 0.0f;
        spk1f[tid] = sp1;
        asm volatile("s_waitcnt lgkmcnt(0)\n\ts_barrier" ::: "memory");  // B1

        // ---- cur2[j] = b2[j] + sum_h spk1[h]*W2[j,h], dense in registers ----
        // Accumulator split matches old sparse kernel: chunks 0,2 -> c2a ; 1,3 -> c2b
        const float4* sv = (const float4*)spk1f;
        float c2a = b2h, c2b = 0.f;
        #pragma unroll
        for (int q = 0; q < 8; ++q) {
            float4 s = sv[q];
            c2a = fmaf(s.x, w2q[q].x, c2a); c2a = fmaf(s.y, w2q[q].y, c2a);
            c2a = fmaf(s.z, w2q[q].z, c2a); c2a = fmaf(s.w, w2q[q].w, c2a);
        }
        #pragma unroll
        for (int q = 8; q < 16; ++q) {
            float4 s = sv[q];
            c2b = fmaf(s.x, w2q[q].x, c2b); c2b = fmaf(s.y, w2q[q].y, c2b);
            c2b = fmaf(s.z, w2q[q].z, c2b); c2b = fmaf(s.w, w2q[q].w, c2b);
        }
        #pragma unroll
        for (int q = 16; q < 24; ++q) {
            float4 s = sv[q];
            c2a = fmaf(s.x, w2q[q].x, c2a); c2a = fmaf(s.y, w2q[q].y, c2a);
            c2a = fmaf(s.z, w2q[q].z, c2a); c2a = fmaf(s.w, w2q[q].w, c2a);
        }
        #pragma unroll
        for (int q = 24; q < 32; ++q) {
            float4 s = sv[q];
            c2b = fmaf(s.x, w2q[q].x, c2b); c2b = fmaf(s.y, w2q[q].y, c2b);
            c2b = fmaf(s.z, w2q[q].z, c2b); c2b = fmaf(s.w, w2q[q].w, c2b);
        }
        const float cur2 = c2a + c2b;

        // ---- LIF2 ----
        const float r2 = (mem2 > 1.0f) ? 1.0f : 0.0f;
        mem2 = bt2 * mem2 + cur2 - r2;
        const float sp2 = ((mem2 - 1.0f) > 0.0f) ? 1.0f : 0.0f;
        spk2f[tid] = sp2;
        asm volatile("s_waitcnt lgkmcnt(0)\n\ts_barrier" ::: "memory");  // B2

        // ---- out partials: thread (g,a) covers j in [16g,16g+16), dense ----
        {
            const float4* s2v = (const float4*)(spk2f + (g << 4));
            float p = 0.f;
            #pragma unroll
            for (int k = 0; k < 4; ++k) {
                float4 s = s2v[k];
                p = fmaf(s.x, w3s[k].x, p); p = fmaf(s.y, w3s[k].y, p);
                p = fmaf(s.z, w3s[k].z, p); p = fmaf(s.w, w3s[k].w, p);
            }
            partials[tid] = p;
        }
        // stage x[t+1] (write into the other buffer; visible after B3)
        xsh[cur ^ 1][tid] = xn;
        asm volatile("s_waitcnt lgkmcnt(0)\n\ts_barrier" ::: "memory");  // B3

        if (tid < AA) {
            float o = b3a;
            #pragma unroll
            for (int gg = 0; gg < 8; ++gg) o += partials[gg * 16 + tid];
            obuf[(t & 7) * AA + tid] = o;
        }

        // flush 8 steps of output as one coalesced 512B store
        if ((t & 7) == 7) {
            asm volatile("s_waitcnt lgkmcnt(0)\n\ts_barrier" ::: "memory");  // B4 (1/8 iters)
            orow[(t - 7) * AA + tid] = obuf[tid];
        }
        xrow += FF;
    }
}

extern "C" void kernel_launch(void* const* d_in, const int* in_sizes, int n_in,
                              void* d_out, int out_size, void* d_ws, size_t ws_size,
                              hipStream_t stream) {
    const float* X     = (const float*)d_in[0];
    const float* hid   = (const float*)d_in[1];
    const float* W1    = (const float*)d_in[2];
    const float* b1    = (const float*)d_in[3];
    const float* beta1 = (const float*)d_in[4];
    const float* W2    = (const float*)d_in[5];
    const float* b2    = (const float*)d_in[6];
    const float* beta2 = (const float*)d_in[7];
    const float* W3    = (const float*)d_in[8];
    const float* b3    = (const float*)d_in[9];
    float* out = (float*)d_out;

    dsqn_fused<<<BB, 128, 0, stream>>>(X, hid, W1, b1, beta1, W2, b2, beta2, W3, b3, out);
}

// Round 2
// 2354.494 us; speedup vs baseline: 1.4096x; 1.4096x over previous
//
#include <hip/hip_runtime.h>
#include <cstdint>
#include <cstddef>

#define BB 512
#define TT 1024
#define FF 128
#define HH 128
#define AA 16

// Barrier that does NOT drain vmcnt (keeps the x prefetch in flight).
#define BAR() asm volatile("s_waitcnt lgkmcnt(0)\n\ts_barrier" ::: "memory")

// 512 threads = 8 waves. Thread t: h = t&127 (owned hidden unit), q = t>>7.
//  cur1: thread (q,h) computes baseline chain s_q = sum_k x[4k+q]*W1[h][4k+q]
//        (32 fmaf, weights in 32 VGPRs). x comes in via v_readlane from a
//        per-wave register holding the row distributed across lanes -> no LDS
//        broadcast. Combine ((p0+p1)+(p2+p3))+b1 == baseline bit-exactly.
//  cur2: threads <256, u=(t>>7)&1: chain c2a (u=0: b2h + words0,2) / c2b
//        (u=1: words1,3), 64 fmaf with SGPR 0.0/1.0 multipliers built from
//        per-wave-uniform ballot words (2 SALU/term). fmaf(1,w,c)==c+w and
//        fmaf(0,w,c)==c exactly -> bit-identical to the sparse walk.
//  out:  threads <128 reproduce the baseline 16-chunk partials (dense fmaf
//        over bit-extracted multipliers), then t<16 do the same sequential
//        8-term reduction. All summation DAGs preserved.
__global__ __launch_bounds__(512, 4) void dsqn_fused(
    const float* __restrict__ X,      // (B,T,F)
    const float* __restrict__ hid,    // (B,1,2,H)
    const float* __restrict__ W1,     // (H,F)
    const float* __restrict__ b1,     // (H)
    const float* __restrict__ beta1,  // (H)
    const float* __restrict__ W2,     // (H,H)
    const float* __restrict__ b2,     // (H)
    const float* __restrict__ beta2,  // (H)
    const float* __restrict__ W3,     // (A,H)
    const float* __restrict__ b3,     // (A)
    float* __restrict__ out)          // (B,T,A)
{
    __shared__ float p1[4 * HH];          // cur1 quarter partials
    __shared__ float p2[2 * HH];          // cur2 half-chain partials
    __shared__ float p3[128];             // out partials
    __shared__ float w3l[128 * 17];       // W3 rows, stride 17 (bank-friendly)
    __shared__ float obuf[8 * AA];        // 8-step output batch
    __shared__ unsigned mw1[4], mw2[4];   // spike masks (32-bit words)

    const int t = threadIdx.x;
    const int b = blockIdx.x;
    const int h = t & 127;
    const int q = t >> 7;       // 0..3
    const int u = q & 1;        // chain index for cur2 (threads < 256)
    const int lane = t & 63;

    // ---- persistent per-thread weights ----
    float w1r[32];              // W1[h][4k+q]
    {
        const float* w1p = W1 + h * FF + q;
        #pragma unroll
        for (int k = 0; k < 32; ++k) w1r[k] = w1p[4 * k];
    }
    float w2a[32], w2b[32];     // u=0: words 0,2 ; u=1: words 1,3
    if (t < 256) {
        const float* w2p = W2 + h * HH + u * 32;
        #pragma unroll
        for (int k = 0; k < 32; ++k) { w2a[k] = w2p[k]; w2b[k] = w2p[64 + k]; }
    }
    // W3 -> LDS: row r = g*16+a holds W3[a][16g+k], stride 17 dwords.
    for (int i = t; i < 128 * 16; i += 512) {
        const int r = i >> 4, k = i & 15;
        const int a = r & 15, g = r >> 4;
        w3l[r * 17 + k] = W3[a * HH + g * 16 + k];
    }

    float mem1 = hid[b * 2 * HH + h];
    float mem2 = hid[b * 2 * HH + HH + h];
    const float b1h = b1[h];
    const float b2h = b2[h];
    const float bt1 = fminf(fmaxf(beta1[h], 0.f), 1.f);
    const float bt2 = fminf(fmaxf(beta2[h], 0.f), 1.f);
    const float b3a = (t < AA) ? b3[t] : 0.f;

    const float* xrow = X + (size_t)b * TT * FF;
    float* orow = out + (size_t)b * TT * AA;

    // x row distributed across lanes: lane l holds x[4*(l&31)+q].
    const int xidx = 4 * (lane & 31) + q;
    float xv = xrow[xidx];

    BAR();  // w3l visible before first use

    for (int st = 0; st < TT; ++st) {
        // prefetch next x (vmcnt never drained by our barriers -> one full
        // step of latency hiding)
        const float xn = (st + 1 < TT) ? xrow[FF + xidx] : 0.f;

        // ---- cur1 partial: chain s_q, f = q,q+4,...,q+124 ascending ----
        float acc = 0.f;
        #pragma unroll
        for (int k = 0; k < 32; ++k) {
            const float xs = __int_as_float(
                __builtin_amdgcn_readlane(__float_as_int(xv), k));
            acc = fmaf(xs, w1r[k], acc);
        }
        p1[t] = acc;
        BAR();  // B1

        // ---- combine + LIF1 (replicated in all 4 q-threads of h) ----
        const float c0 = p1[h], c1 = p1[128 + h], c2 = p1[256 + h], c3 = p1[384 + h];
        const float cur1 = ((c0 + c1) + (c2 + c3)) + b1h;
        const float r1 = (mem1 > 1.0f) ? 1.0f : 0.0f;
        mem1 = bt1 * mem1 + cur1 - r1;
        const int sp1 = (mem1 - 1.0f) > 0.0f;
        {
            const unsigned long long bal = __ballot(sp1);
            if (t == 0)       { mw1[0] = (unsigned)bal; mw1[1] = (unsigned)(bal >> 32); }
            else if (t == 64) { mw1[2] = (unsigned)bal; mw1[3] = (unsigned)(bal >> 32); }
        }
        BAR();  // B2

        // ---- cur2 chains (threads < 256) ----
        if (t < 256) {
            const unsigned wa = __builtin_amdgcn_readfirstlane(mw1[u]);
            const unsigned wb = __builtin_amdgcn_readfirstlane(mw1[2 + u]);
            float c = (u == 0) ? b2h : 0.f;
            #pragma unroll
            for (int k = 0; k < 32; ++k)
                c = fmaf(__uint_as_float(((wa >> k) & 1u) * 0x3f800000u), w2a[k], c);
            #pragma unroll
            for (int k = 0; k < 32; ++k)
                c = fmaf(__uint_as_float(((wb >> k) & 1u) * 0x3f800000u), w2b[k], c);
            p2[u * HH + h] = c;
        }
        BAR();  // B3

        // ---- combine + LIF2 (replicated) ----
        const float cur2 = p2[h] + p2[HH + h];
        const float r2 = (mem2 > 1.0f) ? 1.0f : 0.0f;
        mem2 = bt2 * mem2 + cur2 - r2;
        const int sp2 = (mem2 - 1.0f) > 0.0f;
        {
            const unsigned long long bal = __ballot(sp2);
            if (t == 0)       { mw2[0] = (unsigned)bal; mw2[1] = (unsigned)(bal >> 32); }
            else if (t == 64) { mw2[2] = (unsigned)bal; mw2[3] = (unsigned)(bal >> 32); }
        }
        BAR();  // B4

        // ---- out partials: thread (g,a), chunk = 16 bits of mask2 ----
        if (t < 128) {
            const int g = t >> 4;
            const unsigned wa = __builtin_amdgcn_readfirstlane(mw2[(t >> 6) * 2]);
            const unsigned wb = __builtin_amdgcn_readfirstlane(mw2[(t >> 6) * 2 + 1]);
            const unsigned word = ((t >> 5) & 1) ? wb : wa;
            const unsigned chunk = (word >> ((g & 1) * 16)) & 0xFFFFu;
            float p = 0.f;
            #pragma unroll
            for (int k = 0; k < 16; ++k) {
                const float m = __uint_as_float(((chunk >> k) & 1u) * 0x3f800000u);
                p = fmaf(m, w3l[t * 17 + k], p);
            }
            p3[t] = p;
        }
        BAR();  // B5

        if (t < AA) {
            float o = b3a;
            #pragma unroll
            for (int gg = 0; gg < 8; ++gg) o += p3[gg * 16 + t];
            obuf[(st & 7) * AA + t] = o;
        }

        if ((st & 7) == 7) {
            BAR();  // B6 (1/8 iters)
            if (t < 128) orow[(st - 7) * AA + t] = obuf[t];
        }

        xv = xn;
        xrow += FF;
    }
}

extern "C" void kernel_launch(void* const* d_in, const int* in_sizes, int n_in,
                              void* d_out, int out_size, void* d_ws, size_t ws_size,
                              hipStream_t stream) {
    const float* X     = (const float*)d_in[0];
    const float* hid   = (const float*)d_in[1];
    const float* W1    = (const float*)d_in[2];
    const float* b1    = (const float*)d_in[3];
    const float* beta1 = (const float*)d_in[4];
    const float* W2    = (const float*)d_in[5];
    const float* b2    = (const float*)d_in[6];
    const float* beta2 = (const float*)d_in[7];
    const float* W3    = (const float*)d_in[8];
    const float* b3    = (const float*)d_in[9];
    float* out = (float*)d_out;

    dsqn_fused<<<BB, 512, 0, stream>>>(X, hid, W1, b1, beta1, W2, b2, beta2, W3, b3, out);
}

// Round 3
// 1717.647 us; speedup vs baseline: 1.9322x; 1.3708x over previous
//
#include <hip/hip_runtime.h>
#include <cstdint>
#include <cstddef>

#define BB 512
#define TT 1024
#define FF 128
#define HH 128
#define AA 16

// Barrier that does NOT drain vmcnt (keeps x prefetch in flight).
#define BAR() asm volatile("s_waitcnt lgkmcnt(0)\n\ts_barrier" ::: "memory")

__device__ __forceinline__ float rl(float v, int l) {
    return __int_as_float(__builtin_amdgcn_readlane(__float_as_int(v), l));
}

// 512 threads = 8 waves, one block per batch element.
// Lane l of each wave owns hidden units h0=l, h1=64+l (state replicated per
// wave) so __ballot delivers mask words 0,1 (h 0..63) and 2,3 (h 64..127)
// directly into SGPRs - no LDS mask traffic, no mask barriers.
//  waves 0-3 : LIF1 + cur2 chain (u=(wid>>1)&1 : words u,2+u) + LIF2 + out
//  waves 4-7 : next step's cur1 chains (q=wid&3), x prefetched 2 rows ahead
// All FP summation DAGs identical to the previous passing kernels:
//  cur1 = ((s0+s1)+(s2+s3))+b1 ; s_q = fmaf chain k ascending over x[4k+q]
//  cur2 = c2a+c2b ; c2a = b2 then word0,word2 ascending ; c2b = word1,word3
//  out  = b3 + p3[0..7] sequential ; p3[g] = 16-term fmaf chain ascending
// (fmaf(0,w,c)==c and fmaf(1,w,c)==c+w exactly).
__global__ __launch_bounds__(512, 4) void dsqn_fused(
    const float* __restrict__ X,      // (B,T,F)
    const float* __restrict__ hid,    // (B,1,2,H)
    const float* __restrict__ W1,     // (H,F)
    const float* __restrict__ b1,     // (H)
    const float* __restrict__ beta1,  // (H)
    const float* __restrict__ W2,     // (H,H)
    const float* __restrict__ b2,     // (H)
    const float* __restrict__ beta2,  // (H)
    const float* __restrict__ W3,     // (A,H)
    const float* __restrict__ b3,     // (A)
    float* __restrict__ out)          // (B,T,A)
{
    __shared__ float p1b[2][4 * HH];   // [parity][q*128+h] cur1 partials
    __shared__ float p2[2 * HH];       // [u*128+j] cur2 half-chains
    __shared__ float p3b[2][128];      // [parity][r] out partials
    __shared__ float w3l[128 * 17];    // W3 rows, stride 17 (conflict-free)
    __shared__ float obuf[8 * AA];     // 8-step output batch

    const int t = threadIdx.x;
    const int b = blockIdx.x;
    const int lane = t & 63;
    const int wid = t >> 6;            // 0..7
    const bool isC2 = (wid < 4);
    const int u = (wid >> 1) & 1;      // waves 0,1 -> u=0 ; waves 2,3 -> u=1
    const int q = wid & 3;             // waves 4-7 -> q = wid-4

    // ---- union weight registers (64 floats/thread) ----
    float wA[32], wB[32];
    if (isC2) {
        const float* w2p = W2 + (t & 127) * HH + u * 32;   // j = t&127
        #pragma unroll
        for (int k = 0; k < 32; ++k) { wA[k] = w2p[k]; wB[k] = w2p[64 + k]; }
    } else {
        const float* wa = W1 + lane * FF + q;              // h = lane
        const float* wb = W1 + (64 + lane) * FF + q;       // h = 64+lane
        #pragma unroll
        for (int k = 0; k < 32; ++k) { wA[k] = wa[4 * k]; wB[k] = wb[4 * k]; }
    }
    // W3 -> LDS, row r=g*16+a holds W3[a][16g+k], stride 17 dwords.
    for (int i = t; i < 128 * 16; i += 512) {
        const int r = i >> 4, k = i & 15;
        const int a = r & 15, g = r >> 4;
        w3l[r * 17 + k] = W3[a * HH + g * 16 + k];
    }

    float mem1_0 = hid[b * 2 * HH + lane];
    float mem1_1 = hid[b * 2 * HH + 64 + lane];
    float mem2_0 = hid[b * 2 * HH + HH + lane];
    float mem2_1 = hid[b * 2 * HH + HH + 64 + lane];
    const float b1h0 = b1[lane], b1h1 = b1[64 + lane];
    const float bt1_0 = fminf(fmaxf(beta1[lane], 0.f), 1.f);
    const float bt1_1 = fminf(fmaxf(beta1[64 + lane], 0.f), 1.f);
    const float b2j = b2[t & 127];
    const float bt2_0 = fminf(fmaxf(beta2[lane], 0.f), 1.f);
    const float bt2_1 = fminf(fmaxf(beta2[64 + lane], 0.f), 1.f);
    const float b3a = (t < AA) ? b3[t] : 0.f;

    const float* xrow = X + (size_t)b * TT * FF;
    float* orow = out + (size_t)b * TT * AA;

    const int xidx = 4 * (lane & 31) + q;   // lane k (and k+32) holds x[4k+q]
    float xv = 0.f;

    if (!isC2) {
        // prologue: p1 for step 0 from x[0], then xv = x[1]
        const float xv0 = xrow[xidx];
        float a0 = 0.f, a1 = 0.f;
        #pragma unroll
        for (int k = 0; k < 32; ++k) {
            const float xs = rl(xv0, k);
            a0 = fmaf(xs, wA[k], a0);
            a1 = fmaf(xs, wB[k], a1);
        }
        p1b[0][q * 128 + lane] = a0;
        p1b[0][q * 128 + 64 + lane] = a1;
        xv = xrow[FF + xidx];
    }
    BAR();  // p1(0) + w3l visible

    for (int st = 0; st < TT; ++st) {
        const int par = st & 1;

        if (isC2) {
            // ---- LIF1 (replicated in waves 0-3) ----
            const float* p1c = p1b[par];
            const float c00 = p1c[lane],       c01 = p1c[128 + lane];
            const float c02 = p1c[256 + lane], c03 = p1c[384 + lane];
            const float c10 = p1c[64 + lane],  c11 = p1c[192 + lane];
            const float c12 = p1c[320 + lane], c13 = p1c[448 + lane];
            const float cur1_0 = ((c00 + c01) + (c02 + c03)) + b1h0;
            const float cur1_1 = ((c10 + c11) + (c12 + c13)) + b1h1;
            const float r1_0 = (mem1_0 > 1.0f) ? 1.0f : 0.0f;
            const float r1_1 = (mem1_1 > 1.0f) ? 1.0f : 0.0f;
            mem1_0 = bt1_0 * mem1_0 + cur1_0 - r1_0;
            mem1_1 = bt1_1 * mem1_1 + cur1_1 - r1_1;
            const unsigned long long balA = __ballot((mem1_0 - 1.0f) > 0.0f); // words 0,1
            const unsigned long long balB = __ballot((mem1_1 - 1.0f) > 0.0f); // words 2,3

            // distribute this chain's two mask words as 0/1.0f across lanes:
            // lanes 0-31 = bits of word u, lanes 32-63 = bits of word 2+u
            const unsigned wlo = u ? (unsigned)(balA >> 32) : (unsigned)balA;
            const unsigned whi = u ? (unsigned)(balB >> 32) : (unsigned)balB;
            const unsigned long long packed =
                (unsigned long long)wlo | ((unsigned long long)whi << 32);
            const unsigned bit = (unsigned)(packed >> lane) & 1u;
            const float mflt = bit ? 1.0f : 0.0f;

            // ---- cur2 chain: b2 (u=0) + word_u then word_{2+u}, k ascending
            float c = u ? 0.f : b2j;
            #pragma unroll
            for (int k = 0; k < 32; ++k) c = fmaf(rl(mflt, k), wA[k], c);
            #pragma unroll
            for (int k = 0; k < 32; ++k) c = fmaf(rl(mflt, 32 + k), wB[k], c);
            p2[u * 128 + (t & 127)] = c;
        } else {
            // ---- cur1 chains for step st+1 (waves 4-7) ----
            float a0 = 0.f, a1 = 0.f;
            #pragma unroll
            for (int k = 0; k < 32; ++k) {
                const float xs = rl(xv, k);
                a0 = fmaf(xs, wA[k], a0);
                a1 = fmaf(xs, wB[k], a1);
            }
            float* p1n = p1b[par ^ 1];
            p1n[q * 128 + lane] = a0;
            p1n[q * 128 + 64 + lane] = a1;
            // prefetch x[st+2]; barriers never drain vmcnt
            xv = (st + 2 < TT) ? xrow[2 * FF + xidx] : 0.f;
            xrow += FF;
        }
        BAR();  // B: p2 + p1(next) visible

        if (isC2) {
            // ---- LIF2 (replicated waves 0-3) + out partials ----
            const float cur2_0 = p2[lane] + p2[128 + lane];
            const float cur2_1 = p2[64 + lane] + p2[192 + lane];
            const float r2_0 = (mem2_0 > 1.0f) ? 1.0f : 0.0f;
            const float r2_1 = (mem2_1 > 1.0f) ? 1.0f : 0.0f;
            mem2_0 = bt2_0 * mem2_0 + cur2_0 - r2_0;
            mem2_1 = bt2_1 * mem2_1 + cur2_1 - r2_1;
            const unsigned long long balC = __ballot((mem2_0 - 1.0f) > 0.0f); // words 0,1
            const unsigned long long balD = __ballot((mem2_1 - 1.0f) > 0.0f); // words 2,3

            // row r = t&127 (waves 0&2 / 1&3 duplicate-write identical values)
            const int r = t & 127;
            const int g = r >> 4;
            const int wi = r >> 5;
            const unsigned w0m = (unsigned)balC, w1m = (unsigned)(balC >> 32);
            const unsigned w2m = (unsigned)balD, w3m = (unsigned)(balD >> 32);
            const unsigned word = (wi == 0) ? w0m : (wi == 1) ? w1m
                                : (wi == 2) ? w2m : w3m;
            const unsigned chunk = (word >> ((g & 1) * 16)) & 0xFFFFu;
            float p = 0.f;
            #pragma unroll
            for (int k = 0; k < 16; ++k) {
                const float m = __uint_as_float(((chunk >> k) & 1u) * 0x3f800000u);
                p = fmaf(m, w3l[r * 17 + k], p);
            }
            p3b[par][r] = p;
        }
        BAR();  // C: p3 visible

        if (t < AA) {
            float o = b3a;
            #pragma unroll
            for (int gg = 0; gg < 8; ++gg) o += p3b[par][gg * 16 + t];
            obuf[(st & 7) * AA + t] = o;
        }
        if ((st & 7) == 7) {
            BAR();  // D (1/8 iterations)
            if (t < 128) orow[(st - 7) * AA + t] = obuf[t];
        }
    }
}

extern "C" void kernel_launch(void* const* d_in, const int* in_sizes, int n_in,
                              void* d_out, int out_size, void* d_ws, size_t ws_size,
                              hipStream_t stream) {
    const float* X     = (const float*)d_in[0];
    const float* hid   = (const float*)d_in[1];
    const float* W1    = (const float*)d_in[2];
    const float* b1    = (const float*)d_in[3];
    const float* beta1 = (const float*)d_in[4];
    const float* W2    = (const float*)d_in[5];
    const float* b2    = (const float*)d_in[6];
    const float* beta2 = (const float*)d_in[7];
    const float* W3    = (const float*)d_in[8];
    const float* b3    = (const float*)d_in[9];
    float* out = (float*)d_out;

    dsqn_fused<<<BB, 512, 0, stream>>>(X, hid, W1, b1, beta1, W2, b2, beta2, W3, b3, out);
}